// Round 2
// baseline (273.322 us; speedup 1.0000x reference)
//
#include <hip/hip_runtime.h>
#include <cstdint>
#include <cstddef>

#define TSEQ 512
#define DRNN 64
#define DIN  16
#define HSTR 72        // padded row stride (elements) for h planes: kills pow2 bank stride
#define FSTRIDE 66

typedef float  f32x4  __attribute__((ext_vector_type(4)));
typedef short  s16x4  __attribute__((ext_vector_type(4)));
typedef short  s16x8  __attribute__((ext_vector_type(8)));

__device__ __forceinline__ unsigned short f2bf(float f) {
    unsigned u = __builtin_bit_cast(unsigned, f);
    return (unsigned short)((u + 0x7fffu + ((u >> 16) & 1u)) >> 16);  // RNE
}
__device__ __forceinline__ float bf2f(unsigned short s) {
    return __builtin_bit_cast(float, ((unsigned)s) << 16);
}
__device__ __forceinline__ float tanh_fast(float x) {
    float e = __expf(2.0f * x);
    return 1.0f - __fdividef(2.0f, 1.0f + e);
}

__global__ __launch_bounds__(256) void rnn_fused(
    const float* __restrict__ X,
    const float* __restrict__ Wx,
    const float* __restrict__ Wh,
    const float* __restrict__ bias,
    const float* __restrict__ W1,
    const float* __restrict__ b1,
    const float* __restrict__ W2,
    const float* __restrict__ b2,
    float* __restrict__ out)
{
    // h planes row-major: element (i=batch-row, k=hidden) at i*HSTR + k (bf16)
    __shared__ short plane_hi[2][16 * HSTR];
    __shared__ short plane_lo[2][16 * HSTR];
    __shared__ float feat[3 * 16 * FSTRIDE];  // [s][row][hid], padded stride
    __shared__ float wpart[4][16];

    const int tid  = threadIdx.x;
    const int w    = tid >> 6;       // wave id 0..3 (N-split over hidden cols)
    const int lane = tid & 63;
    const int li   = lane & 15;      // A: batch row; B/D: column within tile
    const int g    = lane >> 4;      // k-group
    const int b0   = blockIdx.x * 16;
    const int jc   = (w << 4) | li;  // this wave's global hidden column

    // ---- persistent B fragments: Wh split hi/lo ----
    // slot k-map (identical for A and B, which is all MFMA needs):
    //   k(c,g,e) = c*32 + (e<4 ? 4g+e : 16+4g+(e-4))
    s16x8 Bhi[2], Blo[2];
    #pragma unroll
    for (int c = 0; c < 2; ++c) {
        #pragma unroll
        for (int e = 0; e < 8; ++e) {
            int k = c * 32 + (e < 4 ? 4 * g + e : 16 + 4 * g + (e - 4));
            float v = Wh[k * DRNN + jc];
            unsigned short hh = f2bf(v);
            Bhi[c][e] = (short)hh;
            Blo[c][e] = (short)f2bf(v - bf2f(hh));
        }
    }
    // Wx fragments: K=16 lives in the e<4 slots (k=4g+e); e>=4 slots zero on BOTH sides
    s16x8 BXhi = {0,0,0,0,0,0,0,0}, BXlo = {0,0,0,0,0,0,0,0};
    #pragma unroll
    for (int e = 0; e < 4; ++e) {
        float v = Wx[(4 * g + e) * DRNN + jc];
        unsigned short hh = f2bf(v);
        BXhi[e] = (short)hh;
        BXlo[e] = (short)f2bf(v - bf2f(hh));
    }
    const float bcol = bias[jc];

    // zero-init h buffer 0 (h_0 = 0)
    for (int idx = tid; idx < 16 * HSTR; idx += 256) {
        plane_hi[0][idx] = 0;
        plane_lo[0][idx] = 0;
    }

    // register-prefetch x: lane (li,g) owns X[b0+li][t][4g..4g+3]
    const float* xrow = X + (size_t)(b0 + li) * TSEQ * DIN + 4 * g;
    f32x4 xcur = *(const f32x4*)(xrow);   // t = 0
    __syncthreads();

    int cb = 0;
    for (int t = 0; t < TSEQ; ++t) {
        const int nb = cb ^ 1;

        // prefetch x_{t+1} (wait lands at the end-of-step barrier drain)
        f32x4 xnext = {0.f, 0.f, 0.f, 0.f};
        if (t + 1 < TSEQ) xnext = *(const f32x4*)(xrow + (size_t)(t + 1) * DIN);

        // A fragments of h: plain contiguous LDS loads, compiler-managed waits
        const short* hb = &plane_hi[cb][li * HSTR + 4 * g];
        const short* lb = &plane_lo[cb][li * HSTR + 4 * g];
        s16x4 h0 = *(const s16x4*)(hb);        // k = 4g+e
        s16x4 h1 = *(const s16x4*)(hb + 16);   // k = 16+4g+e
        s16x4 h2 = *(const s16x4*)(hb + 32);   // k = 32+4g+e
        s16x4 h3 = *(const s16x4*)(hb + 48);   // k = 48+4g+e
        s16x4 l0 = *(const s16x4*)(lb);
        s16x4 l1 = *(const s16x4*)(lb + 16);
        s16x4 l2 = *(const s16x4*)(lb + 32);
        s16x4 l3 = *(const s16x4*)(lb + 48);

        // A fragment of x_t (row=li, k=4g+e in the e<4 slots)
        s16x8 AXhi = {0,0,0,0,0,0,0,0};
        s16x8 AXlo = {0,0,0,0,0,0,0,0};
        #pragma unroll
        for (int e = 0; e < 4; ++e) {
            unsigned short hh = f2bf(xcur[e]);
            AXhi[e] = (short)hh;
            AXlo[e] = (short)f2bf(xcur[e] - bf2f(hh));
        }

        s16x8 Ahi0 = __builtin_shufflevector(h0, h1, 0,1,2,3,4,5,6,7);
        s16x8 Ahi1 = __builtin_shufflevector(h2, h3, 0,1,2,3,4,5,6,7);
        s16x8 Alo0 = __builtin_shufflevector(l0, l1, 0,1,2,3,4,5,6,7);
        s16x8 Alo1 = __builtin_shufflevector(l2, l3, 0,1,2,3,4,5,6,7);

        // hi*hi + lo*hi + hi*lo (drop lo*lo), two chains to shorten serial latency
        f32x4 accA = {0.f, 0.f, 0.f, 0.f};
        f32x4 accB = {0.f, 0.f, 0.f, 0.f};
        accA = __builtin_amdgcn_mfma_f32_16x16x32_bf16(Ahi0, Bhi[0], accA, 0, 0, 0);
        accB = __builtin_amdgcn_mfma_f32_16x16x32_bf16(Ahi1, Bhi[1], accB, 0, 0, 0);
        accA = __builtin_amdgcn_mfma_f32_16x16x32_bf16(Alo0, Bhi[0], accA, 0, 0, 0);
        accB = __builtin_amdgcn_mfma_f32_16x16x32_bf16(Alo1, Bhi[1], accB, 0, 0, 0);
        accA = __builtin_amdgcn_mfma_f32_16x16x32_bf16(Ahi0, Blo[0], accA, 0, 0, 0);
        accB = __builtin_amdgcn_mfma_f32_16x16x32_bf16(Ahi1, Blo[1], accB, 0, 0, 0);
        accA = __builtin_amdgcn_mfma_f32_16x16x32_bf16(AXhi, BXhi,   accA, 0, 0, 0);
        accB = __builtin_amdgcn_mfma_f32_16x16x32_bf16(AXlo, BXhi,   accB, 0, 0, 0);
        accA = __builtin_amdgcn_mfma_f32_16x16x32_bf16(AXhi, BXlo,   accA, 0, 0, 0);
        f32x4 acc = accA + accB;

        // D layout (m89-verified): col = lane&15 (= our jc), rows = 4g+q
        float v0 = tanh_fast(acc[0] + bcol);
        float v1 = tanh_fast(acc[1] + bcol);
        float v2 = tanh_fast(acc[2] + bcol);
        float v3 = tanh_fast(acc[3] + bcol);

        // split hi/lo, store row-major: row 4g+q, col jc
        unsigned short a0 = f2bf(v0), a1 = f2bf(v1), a2 = f2bf(v2), a3 = f2bf(v3);
        plane_hi[nb][(4 * g + 0) * HSTR + jc] = (short)a0;
        plane_hi[nb][(4 * g + 1) * HSTR + jc] = (short)a1;
        plane_hi[nb][(4 * g + 2) * HSTR + jc] = (short)a2;
        plane_hi[nb][(4 * g + 3) * HSTR + jc] = (short)a3;
        plane_lo[nb][(4 * g + 0) * HSTR + jc] = (short)f2bf(v0 - bf2f(a0));
        plane_lo[nb][(4 * g + 1) * HSTR + jc] = (short)f2bf(v1 - bf2f(a1));
        plane_lo[nb][(4 * g + 2) * HSTR + jc] = (short)f2bf(v2 - bf2f(a2));
        plane_lo[nb][(4 * g + 3) * HSTR + jc] = (short)f2bf(v3 - bf2f(a3));

        if (t >= TSEQ - 3) {
            const int s = t - (TSEQ - 3);
            float* fp = &feat[(s * 16 + 4 * g) * FSTRIDE + jc];
            fp[0] = v0; fp[FSTRIDE] = v1; fp[2 * FSTRIDE] = v2; fp[3 * FSTRIDE] = v3;
        }
        __syncthreads();
        cb = nb;
        xcur = xnext;
    }

    // ---- final MLP: out = tanh(tanh(feat) @ W1 + b1) @ W2 + b2 ----
    for (int idx = tid; idx < 3 * 16 * FSTRIDE; idx += 256)
        feat[idx] = tanh_fast(feat[idx]);
    __syncthreads();

    const int r  = tid & 15;   // batch row within block
    const int hc = tid >> 4;   // hidden-chunk 0..15 (8 hid units each)
    float acc8[8];
    #pragma unroll
    for (int u = 0; u < 8; ++u) acc8[u] = b1[hc * 8 + u];
    for (int s = 0; s < 3; ++s) {
        for (int kk = 0; kk < 64; ++kk) {
            float f = feat[(s * 16 + r) * FSTRIDE + kk];
            const float* wr = &W1[(s * 64 + kk) * 128 + hc * 8];
            f32x4 w0  = *(const f32x4*)wr;
            f32x4 w1v = *(const f32x4*)(wr + 4);
            acc8[0] += f * w0[0];  acc8[1] += f * w0[1];
            acc8[2] += f * w0[2];  acc8[3] += f * w0[3];
            acc8[4] += f * w1v[0]; acc8[5] += f * w1v[1];
            acc8[6] += f * w1v[2]; acc8[7] += f * w1v[3];
        }
    }
    float p = 0.f;
    #pragma unroll
    for (int u = 0; u < 8; ++u) p += tanh_fast(acc8[u]) * W2[hc * 8 + u];
    p += __shfl_xor(p, 16);
    p += __shfl_xor(p, 32);
    if (g == 0) wpart[w][li] = p;
    __syncthreads();
    if (tid < 16)
        out[b0 + tid] = wpart[0][tid] + wpart[1][tid] + wpart[2][tid]
                      + wpart[3][tid] + b2[0];
}

extern "C" void kernel_launch(void* const* d_in, const int* in_sizes, int n_in,
                              void* d_out, int out_size, void* d_ws, size_t ws_size,
                              hipStream_t stream) {
    const float* X    = (const float*)d_in[0];
    const float* Wx   = (const float*)d_in[1];
    const float* Wh   = (const float*)d_in[2];
    const float* bias = (const float*)d_in[3];
    const float* W1   = (const float*)d_in[4];
    const float* b1   = (const float*)d_in[5];
    const float* W2   = (const float*)d_in[6];
    const float* b2   = (const float*)d_in[7];
    rnn_fused<<<256, 256, 0, stream>>>(X, Wx, Wh, bias, W1, b1, W2, b2, (float*)d_out);
}

// Round 4
// 270.691 us; speedup vs baseline: 1.0097x; 1.0097x over previous
//
#include <hip/hip_runtime.h>
#include <cstdint>
#include <cstddef>

#define TSEQ 512
#define DRNN 64
#define DIN  16

typedef float  f32x4 __attribute__((ext_vector_type(4)));
typedef short  s16x8 __attribute__((ext_vector_type(8)));
typedef unsigned int u32x4 __attribute__((ext_vector_type(4)));

#define MFMA __builtin_amdgcn_mfma_f32_16x16x32_bf16

// word = (hi16(b) << 16) | hi16(a)   -- one v_perm_b32
__device__ __forceinline__ unsigned pack_hi(float a, float b) {
    return __builtin_amdgcn_perm(__builtin_bit_cast(unsigned, b),
                                 __builtin_bit_cast(unsigned, a), 0x07060302u);
}
__device__ __forceinline__ float bf_trunc(float v) {
    return __builtin_bit_cast(float, __builtin_bit_cast(unsigned, v) & 0xffff0000u);
}
__device__ __forceinline__ s16x8 mk_frag(unsigned w0, unsigned w1, unsigned w2, unsigned w3) {
    u32x4 u = {w0, w1, w2, w3};
    return __builtin_bit_cast(s16x8, u);
}
__device__ __forceinline__ float tanh_fast(float x) {
    // tanh(x) = 1 - 2/(1+exp2(x*2*log2 e)); clean saturation at +/-inf of exp2
    float e = __builtin_amdgcn_exp2f(x * 2.885390082f);
    float r = __builtin_amdgcn_rcpf(1.0f + e);
    return __builtin_fmaf(-2.0f, r, 1.0f);
}

// One recurrence step (computes h_t from h_{t-1}):
//   AIN  : f32x4[4]  = bias + x_t @ Wx   (D layout, consumed)
//   AOUT : f32x4[4]  = bias + x_{t+1} @ Wx  (written)
//   XS   : f32x4 reg holding x_{t+1} slice; consumed, refilled with x_{t+5}
#define STEP(AIN, AOUT, XS, TT) do {                                          \
    f32x4 d0 = AIN[0], d1 = AIN[1], d2 = AIN[2], d3 = AIN[3];                 \
    d0 = MFMA(WhH[0][0], BhH0, d0, 0,0,0);                                    \
    d1 = MFMA(WhH[1][0], BhH0, d1, 0,0,0);                                    \
    d2 = MFMA(WhH[2][0], BhH0, d2, 0,0,0);                                    \
    d3 = MFMA(WhH[3][0], BhH0, d3, 0,0,0);                                    \
    d0 = MFMA(WhL[0][0], BhH0, d0, 0,0,0);                                    \
    d1 = MFMA(WhL[1][0], BhH0, d1, 0,0,0);                                    \
    d2 = MFMA(WhL[2][0], BhH0, d2, 0,0,0);                                    \
    d3 = MFMA(WhL[3][0], BhH0, d3, 0,0,0);                                    \
    d0 = MFMA(WhH[0][0], BhL0, d0, 0,0,0);                                    \
    d1 = MFMA(WhH[1][0], BhL0, d1, 0,0,0);                                    \
    d2 = MFMA(WhH[2][0], BhL0, d2, 0,0,0);                                    \
    d3 = MFMA(WhH[3][0], BhL0, d3, 0,0,0);                                    \
    d0 = MFMA(WhH[0][1], BhH1, d0, 0,0,0);                                    \
    d1 = MFMA(WhH[1][1], BhH1, d1, 0,0,0);                                    \
    d2 = MFMA(WhH[2][1], BhH1, d2, 0,0,0);                                    \
    d3 = MFMA(WhH[3][1], BhH1, d3, 0,0,0);                                    \
    d0 = MFMA(WhL[0][1], BhH1, d0, 0,0,0);                                    \
    d1 = MFMA(WhL[1][1], BhH1, d1, 0,0,0);                                    \
    d2 = MFMA(WhL[2][1], BhH1, d2, 0,0,0);                                    \
    d3 = MFMA(WhL[3][1], BhH1, d3, 0,0,0);                                    \
    d0 = MFMA(WhH[0][1], BhL1, d0, 0,0,0);                                    \
    d1 = MFMA(WhH[1][1], BhL1, d1, 0,0,0);                                    \
    d2 = MFMA(WhH[2][1], BhL1, d2, 0,0,0);                                    \
    d3 = MFMA(WhH[3][1], BhL1, d3, 0,0,0);                                    \
    float v0  = tanh_fast(d0[0]), v1  = tanh_fast(d0[1]);                     \
    float v2  = tanh_fast(d0[2]), v3  = tanh_fast(d0[3]);                     \
    float v4  = tanh_fast(d1[0]), v5  = tanh_fast(d1[1]);                     \
    float v6  = tanh_fast(d1[2]), v7  = tanh_fast(d1[3]);                     \
    float v8  = tanh_fast(d2[0]), v9  = tanh_fast(d2[1]);                     \
    float v10 = tanh_fast(d2[2]), v11 = tanh_fast(d2[3]);                     \
    float v12 = tanh_fast(d3[0]), v13 = tanh_fast(d3[1]);                     \
    float v14 = tanh_fast(d3[2]), v15 = tanh_fast(d3[3]);                     \
    BhH0 = mk_frag(pack_hi(v0,v1),  pack_hi(v2,v3),                           \
                   pack_hi(v4,v5),  pack_hi(v6,v7));                          \
    BhH1 = mk_frag(pack_hi(v8,v9),  pack_hi(v10,v11),                         \
                   pack_hi(v12,v13),pack_hi(v14,v15));                        \
    BhL0 = mk_frag(pack_hi(v0-bf_trunc(v0),   v1-bf_trunc(v1)),               \
                   pack_hi(v2-bf_trunc(v2),   v3-bf_trunc(v3)),               \
                   pack_hi(v4-bf_trunc(v4),   v5-bf_trunc(v5)),               \
                   pack_hi(v6-bf_trunc(v6),   v7-bf_trunc(v7)));              \
    BhL1 = mk_frag(pack_hi(v8-bf_trunc(v8),   v9-bf_trunc(v9)),               \
                   pack_hi(v10-bf_trunc(v10), v11-bf_trunc(v11)),             \
                   pack_hi(v12-bf_trunc(v12), v13-bf_trunc(v13)),             \
                   pack_hi(v14-bf_trunc(v14), v15-bf_trunc(v15)));            \
    if (__builtin_expect((TT) >= TSEQ - 3, 0)) {                              \
        unsigned f0 = pack_hi(tanh_fast(v0),  tanh_fast(v1));                 \
        unsigned f1 = pack_hi(tanh_fast(v2),  tanh_fast(v3));                 \
        unsigned f2 = pack_hi(tanh_fast(v4),  tanh_fast(v5));                 \
        unsigned f3 = pack_hi(tanh_fast(v6),  tanh_fast(v7));                 \
        unsigned f4 = pack_hi(tanh_fast(v8),  tanh_fast(v9));                 \
        unsigned f5 = pack_hi(tanh_fast(v10), tanh_fast(v11));                \
        unsigned f6 = pack_hi(tanh_fast(v12), tanh_fast(v13));                \
        unsigned f7 = pack_hi(tanh_fast(v14), tanh_fast(v15));                \
        s16x8 fa = mk_frag(f0,f1,f2,f3), fb = mk_frag(f4,f5,f6,f7);           \
        if ((TT) == TSEQ - 3)      { feat0 = fa; feat1 = fb; }                \
        else if ((TT) == TSEQ - 2) { feat2 = fa; feat3 = fb; }                \
        else                       { feat4 = fa; feat5 = fb; }                \
    }                                                                         \
    { f32x4 xv = XS;                                                          \
      s16x8 BxH = mk_frag(pack_hi(xv[0], xv[1]), pack_hi(xv[2], xv[3]), 0, 0);\
      s16x8 BxL = mk_frag(pack_hi(xv[0]-bf_trunc(xv[0]), xv[1]-bf_trunc(xv[1])),\
                          pack_hi(xv[2]-bf_trunc(xv[2]), xv[3]-bf_trunc(xv[3])),\
                          0, 0);                                              \
      f32x4 a0 = bfr[0], a1 = bfr[1], a2 = bfr[2], a3 = bfr[3];               \
      a0 = MFMA(WxH[0], BxH, a0, 0,0,0);                                      \
      a1 = MFMA(WxH[1], BxH, a1, 0,0,0);                                      \
      a2 = MFMA(WxH[2], BxH, a2, 0,0,0);                                      \
      a3 = MFMA(WxH[3], BxH, a3, 0,0,0);                                      \
      a0 = MFMA(WxL[0], BxH, a0, 0,0,0);                                      \
      a1 = MFMA(WxL[1], BxH, a1, 0,0,0);                                      \
      a2 = MFMA(WxL[2], BxH, a2, 0,0,0);                                      \
      a3 = MFMA(WxL[3], BxH, a3, 0,0,0);                                      \
      a0 = MFMA(WxH[0], BxL, a0, 0,0,0);                                      \
      a1 = MFMA(WxH[1], BxL, a1, 0,0,0);                                      \
      a2 = MFMA(WxH[2], BxL, a2, 0,0,0);                                      \
      a3 = MFMA(WxH[3], BxL, a3, 0,0,0);                                      \
      AOUT[0] = a0; AOUT[1] = a1; AOUT[2] = a2; AOUT[3] = a3;                 \
      int tl = (TT) + 5; if (tl > TSEQ - 1) tl = TSEQ - 1;                    \
      XS = *(const f32x4*)(xrow + (size_t)tl * DIN);                          \
    }                                                                         \
} while (0)

__global__ __launch_bounds__(64, 1) void rnn_swapped(
    const float* __restrict__ X,
    const float* __restrict__ Wx,
    const float* __restrict__ Wh,
    const float* __restrict__ bias,
    const float* __restrict__ W1,
    const float* __restrict__ b1,
    const float* __restrict__ W2,
    const float* __restrict__ b2,
    float* __restrict__ out)
{
    const int lane = threadIdx.x & 63;
    const int li   = lane & 15;      // batch row within tile (and M/N col for weights)
    const int g    = lane >> 4;      // k-slot group
    const int b0   = blockIdx.x * 16;

    // ---- persistent A fragments: Wh^T (hi/lo by truncation split) ----
    // slot map: k(c,g,e) = c*32 + (e<4 ? 4g+e : 16+4g+(e-4)); A value = Wh[k][16mt+li]
    s16x8 WhH[4][2], WhL[4][2];
    #pragma unroll
    for (int mt = 0; mt < 4; ++mt) {
        #pragma unroll
        for (int c = 0; c < 2; ++c) {
            float wv[8], lv[8];
            #pragma unroll
            for (int e = 0; e < 8; ++e) {
                int k = c * 32 + (e < 4 ? 4 * g + e : 16 + 4 * g + (e - 4));
                wv[e] = Wh[k * DRNN + 16 * mt + li];
                lv[e] = wv[e] - bf_trunc(wv[e]);
            }
            WhH[mt][c] = mk_frag(pack_hi(wv[0],wv[1]), pack_hi(wv[2],wv[3]),
                                 pack_hi(wv[4],wv[5]), pack_hi(wv[6],wv[7]));
            WhL[mt][c] = mk_frag(pack_hi(lv[0],lv[1]), pack_hi(lv[2],lv[3]),
                                 pack_hi(lv[4],lv[5]), pack_hi(lv[6],lv[7]));
        }
    }
    // Wx^T fragments: K=16 in e<4 slots (k=4g+e), upper slots zero
    s16x8 WxH[4], WxL[4];
    #pragma unroll
    for (int mt = 0; mt < 4; ++mt) {
        float wv[4], lv[4];
        #pragma unroll
        for (int e = 0; e < 4; ++e) {
            wv[e] = Wx[(4 * g + e) * DRNN + 16 * mt + li];
            lv[e] = wv[e] - bf_trunc(wv[e]);
        }
        WxH[mt] = mk_frag(pack_hi(wv[0],wv[1]), pack_hi(wv[2],wv[3]), 0, 0);
        WxL[mt] = mk_frag(pack_hi(lv[0],lv[1]), pack_hi(lv[2],lv[3]), 0, 0);
    }
    // bias fragment (D layout: row m = 16mt + 4g + q)
    f32x4 bfr[4];
    #pragma unroll
    for (int mt = 0; mt < 4; ++mt)
        bfr[mt] = *(const f32x4*)(bias + 16 * mt + 4 * g);

    // x pipeline: lane (li,g) owns X[b0+li][t][4g..4g+3]
    const float* xrow = X + (size_t)(b0 + li) * TSEQ * DIN + 4 * g;
    f32x4 x0v = *(const f32x4*)(xrow);
    f32x4 xs1 = *(const f32x4*)(xrow + 1 * DIN);
    f32x4 xs2 = *(const f32x4*)(xrow + 2 * DIN);
    f32x4 xs3 = *(const f32x4*)(xrow + 3 * DIN);
    f32x4 xs4 = *(const f32x4*)(xrow + 4 * DIN);

    // prologue: xaccA = bias + x_0 @ Wx
    f32x4 xaccA[4], xaccB[4];
    {
        s16x8 BxH = mk_frag(pack_hi(x0v[0], x0v[1]), pack_hi(x0v[2], x0v[3]), 0, 0);
        s16x8 BxL = mk_frag(pack_hi(x0v[0]-bf_trunc(x0v[0]), x0v[1]-bf_trunc(x0v[1])),
                            pack_hi(x0v[2]-bf_trunc(x0v[2]), x0v[3]-bf_trunc(x0v[3])),
                            0, 0);
        #pragma unroll
        for (int mt = 0; mt < 4; ++mt) {
            f32x4 a = bfr[mt];
            a = MFMA(WxH[mt], BxH, a, 0,0,0);
            a = MFMA(WxL[mt], BxH, a, 0,0,0);
            a = MFMA(WxH[mt], BxL, a, 0,0,0);
            xaccA[mt] = a;
        }
    }
    // h_{-1} = 0
    s16x8 BhH0 = mk_frag(0,0,0,0), BhH1 = mk_frag(0,0,0,0);
    s16x8 BhL0 = mk_frag(0,0,0,0), BhL1 = mk_frag(0,0,0,0);
    s16x8 feat0 = mk_frag(0,0,0,0), feat1 = mk_frag(0,0,0,0);
    s16x8 feat2 = mk_frag(0,0,0,0), feat3 = mk_frag(0,0,0,0);
    s16x8 feat4 = mk_frag(0,0,0,0), feat5 = mk_frag(0,0,0,0);

    for (int tb = 0; tb < TSEQ; tb += 4) {
        STEP(xaccA, xaccB, xs1, tb);
        STEP(xaccB, xaccA, xs2, tb + 1);
        STEP(xaccA, xaccB, xs3, tb + 2);
        STEP(xaccB, xaccA, xs4, tb + 3);
    }

    // ---- MLP: out = tanh(feat @ W1 + b1) @ W2 + b2, feat frags in regs ----
    float p0 = 0.f, p1 = 0.f, p2 = 0.f, p3 = 0.f;
    #pragma unroll
    for (int nt = 0; nt < 8; ++nt) {
        float b1v = b1[nt * 16 + li];
        f32x4 a1 = {b1v, b1v, b1v, b1v};
        #pragma unroll
        for (int c6 = 0; c6 < 6; ++c6) {
            float wv[8];
            #pragma unroll
            for (int e = 0; e < 8; ++e) {
                int k = c6 * 32 + (e < 4 ? 4 * g + e : 16 + 4 * g + (e - 4));
                wv[e] = W1[k * 128 + nt * 16 + li];
            }
            s16x8 wf = mk_frag(pack_hi(wv[0],wv[1]), pack_hi(wv[2],wv[3]),
                               pack_hi(wv[4],wv[5]), pack_hi(wv[6],wv[7]));
            s16x8 af = (c6 == 0) ? feat0 : (c6 == 1) ? feat1 : (c6 == 2) ? feat2
                     : (c6 == 3) ? feat3 : (c6 == 4) ? feat4 : feat5;
            a1 = MFMA(af, wf, a1, 0,0,0);
        }
        float w2v = W2[nt * 16 + li];
        p0 += tanh_fast(a1[0]) * w2v;
        p1 += tanh_fast(a1[1]) * w2v;
        p2 += tanh_fast(a1[2]) * w2v;
        p3 += tanh_fast(a1[3]) * w2v;
    }
    p0 += __shfl_xor(p0, 1); p0 += __shfl_xor(p0, 2);
    p0 += __shfl_xor(p0, 4); p0 += __shfl_xor(p0, 8);
    p1 += __shfl_xor(p1, 1); p1 += __shfl_xor(p1, 2);
    p1 += __shfl_xor(p1, 4); p1 += __shfl_xor(p1, 8);
    p2 += __shfl_xor(p2, 1); p2 += __shfl_xor(p2, 2);
    p2 += __shfl_xor(p2, 4); p2 += __shfl_xor(p2, 8);
    p3 += __shfl_xor(p3, 1); p3 += __shfl_xor(p3, 2);
    p3 += __shfl_xor(p3, 4); p3 += __shfl_xor(p3, 8);
    float b2v = b2[0];
    if (li == 0) out[b0 + 4 * g + 0] = p0 + b2v;
    if (li == 1) out[b0 + 4 * g + 1] = p1 + b2v;
    if (li == 2) out[b0 + 4 * g + 2] = p2 + b2v;
    if (li == 3) out[b0 + 4 * g + 3] = p3 + b2v;
}

extern "C" void kernel_launch(void* const* d_in, const int* in_sizes, int n_in,
                              void* d_out, int out_size, void* d_ws, size_t ws_size,
                              hipStream_t stream) {
    const float* X    = (const float*)d_in[0];
    const float* Wx   = (const float*)d_in[1];
    const float* Wh   = (const float*)d_in[2];
    const float* bias = (const float*)d_in[3];
    const float* W1   = (const float*)d_in[4];
    const float* b1   = (const float*)d_in[5];
    const float* W2   = (const float*)d_in[6];
    const float* b2   = (const float*)d_in[7];
    rnn_swapped<<<256, 64, 0, stream>>>(X, Wx, Wh, bias, W1, b1, W2, b2, (float*)d_out);
}

// Round 5
// 261.041 us; speedup vs baseline: 1.0470x; 1.0370x over previous
//
#include <hip/hip_runtime.h>
#include <cstdint>
#include <cstddef>

#define TSEQ 512
#define DRNN 64
#define DIN  16

typedef float  f32x4 __attribute__((ext_vector_type(4)));
typedef short  s16x8 __attribute__((ext_vector_type(8)));
typedef unsigned int u32x4 __attribute__((ext_vector_type(4)));

#define MFMA __builtin_amdgcn_mfma_f32_16x16x32_bf16

// word = (hi16(b) << 16) | hi16(a)   -- one v_perm_b32
__device__ __forceinline__ unsigned pack_hi(float a, float b) {
    return __builtin_amdgcn_perm(__builtin_bit_cast(unsigned, b),
                                 __builtin_bit_cast(unsigned, a), 0x07060302u);
}
__device__ __forceinline__ float bf_trunc(float v) {
    return __builtin_bit_cast(float, __builtin_bit_cast(unsigned, v) & 0xffff0000u);
}
__device__ __forceinline__ s16x8 mk_frag(unsigned w0, unsigned w1, unsigned w2, unsigned w3) {
    u32x4 u = {w0, w1, w2, w3};
    return __builtin_bit_cast(s16x8, u);
}
__device__ __forceinline__ float tanh_fast(float x) {
    // tanh(x) = 1 - 2/(1+exp2(x*2*log2 e))
    float e = __builtin_amdgcn_exp2f(x * 2.885390082f);
    float r = __builtin_amdgcn_rcpf(1.0f + e);
    return __builtin_fmaf(-2.0f, r, 1.0f);
}

// One recurrence step: h single-bf16 (no lo plane); accumulators split into
// P (c0 half, seeded with bias+x@Wx) and Q (c1 half, seeded 0) -> depth-2 chains.
#define STEP(AIN, AOUT, XS, TT) do {                                          \
    f32x4 P0 = AIN[0], P1 = AIN[1], P2 = AIN[2], P3 = AIN[3];                 \
    P0 = MFMA(WhH[0][0], BhH0, P0, 0,0,0);                                    \
    P1 = MFMA(WhH[1][0], BhH0, P1, 0,0,0);                                    \
    P2 = MFMA(WhH[2][0], BhH0, P2, 0,0,0);                                    \
    P3 = MFMA(WhH[3][0], BhH0, P3, 0,0,0);                                    \
    f32x4 Q0 = MFMA(WhH[0][1], BhH1, zero4, 0,0,0);                           \
    f32x4 Q1 = MFMA(WhH[1][1], BhH1, zero4, 0,0,0);                           \
    f32x4 Q2 = MFMA(WhH[2][1], BhH1, zero4, 0,0,0);                           \
    f32x4 Q3 = MFMA(WhH[3][1], BhH1, zero4, 0,0,0);                           \
    P0 = MFMA(WhL[0][0], BhH0, P0, 0,0,0);                                    \
    P1 = MFMA(WhL[1][0], BhH0, P1, 0,0,0);                                    \
    P2 = MFMA(WhL[2][0], BhH0, P2, 0,0,0);                                    \
    P3 = MFMA(WhL[3][0], BhH0, P3, 0,0,0);                                    \
    Q0 = MFMA(WhL[0][1], BhH1, Q0, 0,0,0);                                    \
    Q1 = MFMA(WhL[1][1], BhH1, Q1, 0,0,0);                                    \
    Q2 = MFMA(WhL[2][1], BhH1, Q2, 0,0,0);                                    \
    Q3 = MFMA(WhL[3][1], BhH1, Q3, 0,0,0);                                    \
    f32x4 d0 = P0 + Q0, d1 = P1 + Q1;                                         \
    float v0 = tanh_fast(d0[0]), v1 = tanh_fast(d0[1]);                       \
    float v2 = tanh_fast(d0[2]), v3 = tanh_fast(d0[3]);                       \
    float v4 = tanh_fast(d1[0]), v5 = tanh_fast(d1[1]);                       \
    float v6 = tanh_fast(d1[2]), v7 = tanh_fast(d1[3]);                       \
    BhH0 = mk_frag(pack_hi(v0,v1), pack_hi(v2,v3),                            \
                   pack_hi(v4,v5), pack_hi(v6,v7));                           \
    f32x4 d2 = P2 + Q2, d3 = P3 + Q3;                                         \
    float v8  = tanh_fast(d2[0]), v9  = tanh_fast(d2[1]);                     \
    float v10 = tanh_fast(d2[2]), v11 = tanh_fast(d2[3]);                     \
    float v12 = tanh_fast(d3[0]), v13 = tanh_fast(d3[1]);                     \
    float v14 = tanh_fast(d3[2]), v15 = tanh_fast(d3[3]);                     \
    BhH1 = mk_frag(pack_hi(v8,v9),   pack_hi(v10,v11),                        \
                   pack_hi(v12,v13), pack_hi(v14,v15));                       \
    if (__builtin_expect((TT) >= TSEQ - 3, 0)) {                              \
        float f0 = tanh_fast(v0),  f1 = tanh_fast(v1);                        \
        float f2 = tanh_fast(v2),  f3 = tanh_fast(v3);                        \
        float f4 = tanh_fast(v4),  f5 = tanh_fast(v5);                        \
        float f6 = tanh_fast(v6),  f7 = tanh_fast(v7);                        \
        float f8 = tanh_fast(v8),  f9 = tanh_fast(v9);                        \
        float f10= tanh_fast(v10), f11= tanh_fast(v11);                       \
        float f12= tanh_fast(v12), f13= tanh_fast(v13);                       \
        float f14= tanh_fast(v14), f15= tanh_fast(v15);                       \
        s16x8 faH = mk_frag(pack_hi(f0,f1),  pack_hi(f2,f3),                  \
                            pack_hi(f4,f5),  pack_hi(f6,f7));                 \
        s16x8 fbH = mk_frag(pack_hi(f8,f9),  pack_hi(f10,f11),                \
                            pack_hi(f12,f13),pack_hi(f14,f15));               \
        s16x8 faL = mk_frag(pack_hi(f0-bf_trunc(f0),  f1-bf_trunc(f1)),       \
                            pack_hi(f2-bf_trunc(f2),  f3-bf_trunc(f3)),       \
                            pack_hi(f4-bf_trunc(f4),  f5-bf_trunc(f5)),       \
                            pack_hi(f6-bf_trunc(f6),  f7-bf_trunc(f7)));      \
        s16x8 fbL = mk_frag(pack_hi(f8-bf_trunc(f8),  f9-bf_trunc(f9)),       \
                            pack_hi(f10-bf_trunc(f10),f11-bf_trunc(f11)),     \
                            pack_hi(f12-bf_trunc(f12),f13-bf_trunc(f13)),     \
                            pack_hi(f14-bf_trunc(f14),f15-bf_trunc(f15)));    \
        if ((TT) == TSEQ - 3)      { featH0=faH; featH1=fbH; featL0=faL; featL1=fbL; } \
        else if ((TT) == TSEQ - 2) { featH2=faH; featH3=fbH; featL2=faL; featL3=fbL; } \
        else                       { featH4=faH; featH5=fbH; featL4=faL; featL5=fbL; } \
    }                                                                         \
    { f32x4 xv = XS;                                                          \
      s16x8 BxH = mk_frag(pack_hi(xv[0], xv[1]), pack_hi(xv[2], xv[3]), 0, 0);\
      s16x8 BxL = mk_frag(pack_hi(xv[0]-bf_trunc(xv[0]), xv[1]-bf_trunc(xv[1])),\
                          pack_hi(xv[2]-bf_trunc(xv[2]), xv[3]-bf_trunc(xv[3])),\
                          0, 0);                                              \
      f32x4 a0 = bfr[0], a1 = bfr[1], a2 = bfr[2], a3 = bfr[3];               \
      a0 = MFMA(WxH[0], BxH, a0, 0,0,0);                                      \
      a1 = MFMA(WxH[1], BxH, a1, 0,0,0);                                      \
      a2 = MFMA(WxH[2], BxH, a2, 0,0,0);                                      \
      a3 = MFMA(WxH[3], BxH, a3, 0,0,0);                                      \
      a0 = MFMA(WxL[0], BxH, a0, 0,0,0);                                      \
      a1 = MFMA(WxL[1], BxH, a1, 0,0,0);                                      \
      a2 = MFMA(WxL[2], BxH, a2, 0,0,0);                                      \
      a3 = MFMA(WxL[3], BxH, a3, 0,0,0);                                      \
      a0 = MFMA(WxH[0], BxL, a0, 0,0,0);                                      \
      a1 = MFMA(WxH[1], BxL, a1, 0,0,0);                                      \
      a2 = MFMA(WxH[2], BxL, a2, 0,0,0);                                      \
      a3 = MFMA(WxH[3], BxL, a3, 0,0,0);                                      \
      AOUT[0] = a0; AOUT[1] = a1; AOUT[2] = a2; AOUT[3] = a3;                 \
      int tl = (TT) + 5; if (tl > TSEQ - 1) tl = TSEQ - 1;                    \
      XS = *(const f32x4*)(xrow + (size_t)tl * DIN);                          \
    }                                                                         \
} while (0)

__global__ __launch_bounds__(64, 1) void rnn_swapped(
    const float* __restrict__ X,
    const float* __restrict__ Wx,
    const float* __restrict__ Wh,
    const float* __restrict__ bias,
    const float* __restrict__ W1,
    const float* __restrict__ b1,
    const float* __restrict__ W2,
    const float* __restrict__ b2,
    float* __restrict__ out)
{
    const int lane = threadIdx.x & 63;
    const int li   = lane & 15;      // batch row within tile (and M/N col for weights)
    const int g    = lane >> 4;      // k-slot group
    const int b0   = blockIdx.x * 16;
    const f32x4 zero4 = {0.f, 0.f, 0.f, 0.f};

    // ---- persistent A fragments: Wh^T (hi/lo by truncation split) ----
    // slot map: k(c,g,e) = c*32 + (e<4 ? 4g+e : 16+4g+(e-4)); A value = Wh[k][16mt+li]
    s16x8 WhH[4][2], WhL[4][2];
    #pragma unroll
    for (int mt = 0; mt < 4; ++mt) {
        #pragma unroll
        for (int c = 0; c < 2; ++c) {
            float wv[8], lv[8];
            #pragma unroll
            for (int e = 0; e < 8; ++e) {
                int k = c * 32 + (e < 4 ? 4 * g + e : 16 + 4 * g + (e - 4));
                wv[e] = Wh[k * DRNN + 16 * mt + li];
                lv[e] = wv[e] - bf_trunc(wv[e]);
            }
            WhH[mt][c] = mk_frag(pack_hi(wv[0],wv[1]), pack_hi(wv[2],wv[3]),
                                 pack_hi(wv[4],wv[5]), pack_hi(wv[6],wv[7]));
            WhL[mt][c] = mk_frag(pack_hi(lv[0],lv[1]), pack_hi(lv[2],lv[3]),
                                 pack_hi(lv[4],lv[5]), pack_hi(lv[6],lv[7]));
        }
    }
    // Wx^T fragments: K=16 in e<4 slots (k=4g+e), upper slots zero
    s16x8 WxH[4], WxL[4];
    #pragma unroll
    for (int mt = 0; mt < 4; ++mt) {
        float wv[4], lv[4];
        #pragma unroll
        for (int e = 0; e < 4; ++e) {
            wv[e] = Wx[(4 * g + e) * DRNN + 16 * mt + li];
            lv[e] = wv[e] - bf_trunc(wv[e]);
        }
        WxH[mt] = mk_frag(pack_hi(wv[0],wv[1]), pack_hi(wv[2],wv[3]), 0, 0);
        WxL[mt] = mk_frag(pack_hi(lv[0],lv[1]), pack_hi(lv[2],lv[3]), 0, 0);
    }
    // bias fragment (D layout: row m = 16mt + 4g + q)
    f32x4 bfr[4];
    #pragma unroll
    for (int mt = 0; mt < 4; ++mt)
        bfr[mt] = *(const f32x4*)(bias + 16 * mt + 4 * g);

    // x pipeline: lane (li,g) owns X[b0+li][t][4g..4g+3]
    const float* xrow = X + (size_t)(b0 + li) * TSEQ * DIN + 4 * g;
    f32x4 x0v = *(const f32x4*)(xrow);
    f32x4 xs1 = *(const f32x4*)(xrow + 1 * DIN);
    f32x4 xs2 = *(const f32x4*)(xrow + 2 * DIN);
    f32x4 xs3 = *(const f32x4*)(xrow + 3 * DIN);
    f32x4 xs4 = *(const f32x4*)(xrow + 4 * DIN);

    // prologue: xaccA = bias + x_0 @ Wx
    f32x4 xaccA[4], xaccB[4];
    {
        s16x8 BxH = mk_frag(pack_hi(x0v[0], x0v[1]), pack_hi(x0v[2], x0v[3]), 0, 0);
        s16x8 BxL = mk_frag(pack_hi(x0v[0]-bf_trunc(x0v[0]), x0v[1]-bf_trunc(x0v[1])),
                            pack_hi(x0v[2]-bf_trunc(x0v[2]), x0v[3]-bf_trunc(x0v[3])),
                            0, 0);
        #pragma unroll
        for (int mt = 0; mt < 4; ++mt) {
            f32x4 a = bfr[mt];
            a = MFMA(WxH[mt], BxH, a, 0,0,0);
            a = MFMA(WxL[mt], BxH, a, 0,0,0);
            a = MFMA(WxH[mt], BxL, a, 0,0,0);
            xaccA[mt] = a;
        }
    }
    // h_{-1} = 0
    s16x8 BhH0 = mk_frag(0,0,0,0), BhH1 = mk_frag(0,0,0,0);
    s16x8 featH0 = mk_frag(0,0,0,0), featH1 = mk_frag(0,0,0,0);
    s16x8 featH2 = mk_frag(0,0,0,0), featH3 = mk_frag(0,0,0,0);
    s16x8 featH4 = mk_frag(0,0,0,0), featH5 = mk_frag(0,0,0,0);
    s16x8 featL0 = mk_frag(0,0,0,0), featL1 = mk_frag(0,0,0,0);
    s16x8 featL2 = mk_frag(0,0,0,0), featL3 = mk_frag(0,0,0,0);
    s16x8 featL4 = mk_frag(0,0,0,0), featL5 = mk_frag(0,0,0,0);

    for (int tb = 0; tb < TSEQ; tb += 4) {
        STEP(xaccA, xaccB, xs1, tb);
        STEP(xaccB, xaccA, xs2, tb + 1);
        STEP(xaccA, xaccB, xs3, tb + 2);
        STEP(xaccB, xaccA, xs4, tb + 3);
    }

    // ---- MLP: out = tanh(feat @ W1 + b1) @ W2 + b2; feat & W1 in hi/lo ----
    float p0 = 0.f, p1 = 0.f, p2 = 0.f, p3 = 0.f;
    #pragma unroll
    for (int nt = 0; nt < 8; ++nt) {
        float b1v = b1[nt * 16 + li];
        f32x4 a1 = {b1v, b1v, b1v, b1v};
        f32x4 a1b = zero4;
        #pragma unroll
        for (int c6 = 0; c6 < 6; ++c6) {
            float wv[8], lv[8];
            #pragma unroll
            for (int e = 0; e < 8; ++e) {
                int k = c6 * 32 + (e < 4 ? 4 * g + e : 16 + 4 * g + (e - 4));
                wv[e] = W1[k * 128 + nt * 16 + li];
                lv[e] = wv[e] - bf_trunc(wv[e]);
            }
            s16x8 wH = mk_frag(pack_hi(wv[0],wv[1]), pack_hi(wv[2],wv[3]),
                               pack_hi(wv[4],wv[5]), pack_hi(wv[6],wv[7]));
            s16x8 wL = mk_frag(pack_hi(lv[0],lv[1]), pack_hi(lv[2],lv[3]),
                               pack_hi(lv[4],lv[5]), pack_hi(lv[6],lv[7]));
            s16x8 aH = (c6==0)?featH0:(c6==1)?featH1:(c6==2)?featH2
                     :(c6==3)?featH3:(c6==4)?featH4:featH5;
            s16x8 aL = (c6==0)?featL0:(c6==1)?featL1:(c6==2)?featL2
                     :(c6==3)?featL3:(c6==4)?featL4:featL5;
            a1  = MFMA(aH, wH, a1, 0,0,0);
            a1b = MFMA(aL, wH, a1b, 0,0,0);
            a1b = MFMA(aH, wL, a1b, 0,0,0);
        }
        a1 = a1 + a1b;
        float w2v = W2[nt * 16 + li];
        p0 += tanh_fast(a1[0]) * w2v;
        p1 += tanh_fast(a1[1]) * w2v;
        p2 += tanh_fast(a1[2]) * w2v;
        p3 += tanh_fast(a1[3]) * w2v;
    }
    p0 += __shfl_xor(p0, 1); p0 += __shfl_xor(p0, 2);
    p0 += __shfl_xor(p0, 4); p0 += __shfl_xor(p0, 8);
    p1 += __shfl_xor(p1, 1); p1 += __shfl_xor(p1, 2);
    p1 += __shfl_xor(p1, 4); p1 += __shfl_xor(p1, 8);
    p2 += __shfl_xor(p2, 1); p2 += __shfl_xor(p2, 2);
    p2 += __shfl_xor(p2, 4); p2 += __shfl_xor(p2, 8);
    p3 += __shfl_xor(p3, 1); p3 += __shfl_xor(p3, 2);
    p3 += __shfl_xor(p3, 4); p3 += __shfl_xor(p3, 8);
    float b2v = b2[0];
    if (li == 0) out[b0 + 4 * g + 0] = p0 + b2v;
    if (li == 1) out[b0 + 4 * g + 1] = p1 + b2v;
    if (li == 2) out[b0 + 4 * g + 2] = p2 + b2v;
    if (li == 3) out[b0 + 4 * g + 3] = p3 + b2v;
}

extern "C" void kernel_launch(void* const* d_in, const int* in_sizes, int n_in,
                              void* d_out, int out_size, void* d_ws, size_t ws_size,
                              hipStream_t stream) {
    const float* X    = (const float*)d_in[0];
    const float* Wx   = (const float*)d_in[1];
    const float* Wh   = (const float*)d_in[2];
    const float* bias = (const float*)d_in[3];
    const float* W1   = (const float*)d_in[4];
    const float* b1   = (const float*)d_in[5];
    const float* W2   = (const float*)d_in[6];
    const float* b2   = (const float*)d_in[7];
    rnn_swapped<<<256, 64, 0, stream>>>(X, Wx, Wh, bias, W1, b1, W2, b2, (float*)d_out);
}

// Round 6
// 168.378 us; speedup vs baseline: 1.6233x; 1.5503x over previous
//
#include <hip/hip_runtime.h>
#include <cstdint>
#include <cstddef>

#define TSEQ 512
#define DRNN 64
#define DIN  16
#define FSTRIDE 66

typedef float  f32x4 __attribute__((ext_vector_type(4)));
typedef short  s16x8 __attribute__((ext_vector_type(8)));
typedef unsigned int u32x4 __attribute__((ext_vector_type(4)));

#define MFMA __builtin_amdgcn_mfma_f32_16x16x32_bf16

// word = (hi16(b) << 16) | hi16(a)   -- one v_perm_b32
__device__ __forceinline__ unsigned pack_hi(float a, float b) {
    return __builtin_amdgcn_perm(__builtin_bit_cast(unsigned, b),
                                 __builtin_bit_cast(unsigned, a), 0x07060302u);
}
__device__ __forceinline__ float bf_trunc(float v) {
    return __builtin_bit_cast(float, __builtin_bit_cast(unsigned, v) & 0xffff0000u);
}
__device__ __forceinline__ s16x8 mk_frag(unsigned w0, unsigned w1, unsigned w2, unsigned w3) {
    u32x4 u = {w0, w1, w2, w3};
    return __builtin_bit_cast(s16x8, u);
}
__device__ __forceinline__ float tanh_fast(float x) {
    float e = __builtin_amdgcn_exp2f(x * 2.885390082f);
    float r = __builtin_amdgcn_rcpf(1.0f + e);
    return __builtin_fmaf(-2.0f, r, 1.0f);
}

// One recurrence step for the 4-wave hidden-split structure.
// PR/PW: read/write halves of the pair-exchange buffer hx (unsigned[32][17]).
// XS: register holding x_{TT+1} slice; consumed for x-proj of step TT+1,
//     refilled with x_{TT+5}.
#define STEP(PR, PW, XS, TT) do {                                             \
    /* B-fragments of h_{TT-1}: 8 pair-words from LDS */                      \
    unsigned c00_ = PR[2*g][li],      c01_ = PR[2*g+1][li];                   \
    unsigned c02_ = PR[8+2*g][li],    c03_ = PR[8+2*g+1][li];                 \
    unsigned c10_ = PR[16+2*g][li],   c11_ = PR[16+2*g+1][li];                \
    unsigned c12_ = PR[24+2*g][li],   c13_ = PR[24+2*g+1][li];                \
    /* x-projection for NEXT step (independent -> hides LDS latency) */       \
    f32x4 xv_ = XS;                                                           \
    s16x8 BxH_ = mk_frag(pack_hi(xv_[0],xv_[1]), pack_hi(xv_[2],xv_[3]),0,0); \
    s16x8 BxL_ = mk_frag(pack_hi(xv_[0]-bf_trunc(xv_[0]),                     \
                                 xv_[1]-bf_trunc(xv_[1])),                    \
                         pack_hi(xv_[2]-bf_trunc(xv_[2]),                     \
                                 xv_[3]-bf_trunc(xv_[3])), 0, 0);             \
    f32x4 xn_ = bfr;                                                          \
    xn_ = MFMA(WxH, BxH_, xn_, 0,0,0);                                        \
    xn_ = MFMA(WxL, BxH_, xn_, 0,0,0);                                        \
    xn_ = MFMA(WxH, BxL_, xn_, 0,0,0);                                        \
    { int tl_ = (TT) + 5; if (tl_ > TSEQ - 1) tl_ = TSEQ - 1;                 \
      XS = *(const f32x4*)(xrow + (size_t)tl_ * DIN); }                       \
    /* h-update MFMAs (compiler inserts lgkmcnt waits for the LDS reads) */   \
    s16x8 BhH0_ = mk_frag(c00_, c01_, c02_, c03_);                            \
    s16x8 BhH1_ = mk_frag(c10_, c11_, c12_, c13_);                            \
    f32x4 P_ = MFMA(WhH[0], BhH0_, xacc, 0,0,0);                              \
    P_ = MFMA(WhL[0], BhH0_, P_, 0,0,0);                                      \
    f32x4 Q_ = MFMA(WhH[1], BhH1_, zero4, 0,0,0);                             \
    Q_ = MFMA(WhL[1], BhH1_, Q_, 0,0,0);                                      \
    f32x4 d_ = P_ + Q_;                                                       \
    float v0_ = tanh_fast(d_[0]), v1_ = tanh_fast(d_[1]);                     \
    float v2_ = tanh_fast(d_[2]), v3_ = tanh_fast(d_[3]);                     \
    PW[8*w + 2*g][li]     = pack_hi(v0_, v1_);                                \
    PW[8*w + 2*g + 1][li] = pack_hi(v2_, v3_);                                \
    if (__builtin_expect((TT) >= TSEQ - 3, 0)) {                              \
        const int s_ = (TT) - (TSEQ - 3);                                     \
        float* fp_ = &feat[(s_ * 16 + li) * FSTRIDE + 16*w + 4*g];            \
        fp_[0] = tanh_fast(v0_); fp_[1] = tanh_fast(v1_);                     \
        fp_[2] = tanh_fast(v2_); fp_[3] = tanh_fast(v3_);                     \
    }                                                                         \
    asm volatile("s_waitcnt lgkmcnt(0)" ::: "memory");                        \
    __builtin_amdgcn_sched_barrier(0);                                        \
    __builtin_amdgcn_s_barrier();                                             \
    __builtin_amdgcn_sched_barrier(0);                                        \
    xacc = xn_;                                                               \
} while (0)

__global__ __launch_bounds__(256, 1) void rnn_w4(
    const float* __restrict__ X,
    const float* __restrict__ Wx,
    const float* __restrict__ Wh,
    const float* __restrict__ bias,
    const float* __restrict__ W1,
    const float* __restrict__ b1,
    const float* __restrict__ W2,
    const float* __restrict__ b2,
    float* __restrict__ out)
{
    // pair-exchange buffers: hx[buf][pair k/2][batch row], padded 17 dwords
    __shared__ unsigned hx[2][32][17];
    __shared__ float feat[3 * 16 * FSTRIDE];
    __shared__ float wpart[4][16];

    const int tid  = threadIdx.x;
    const int w    = tid >> 6;       // wave id = hidden tile mt
    const int lane = tid & 63;
    const int li   = lane & 15;      // batch row within tile
    const int g    = lane >> 4;      // k-slot group
    const int b0   = blockIdx.x * 16;
    const f32x4 zero4 = {0.f, 0.f, 0.f, 0.f};

    // ---- persistent A fragments for THIS wave's hidden tile (mt = w) ----
    // slot map: k(c,g,e) = c*32 + (e<4 ? 4g+e : 16+4g+(e-4)); value Wh[k][16w+li]
    s16x8 WhH[2], WhL[2];
    #pragma unroll
    for (int c = 0; c < 2; ++c) {
        float wv[8], lv[8];
        #pragma unroll
        for (int e = 0; e < 8; ++e) {
            int k = c * 32 + (e < 4 ? 4 * g + e : 16 + 4 * g + (e - 4));
            wv[e] = Wh[k * DRNN + 16 * w + li];
            lv[e] = wv[e] - bf_trunc(wv[e]);
        }
        WhH[c] = mk_frag(pack_hi(wv[0],wv[1]), pack_hi(wv[2],wv[3]),
                         pack_hi(wv[4],wv[5]), pack_hi(wv[6],wv[7]));
        WhL[c] = mk_frag(pack_hi(lv[0],lv[1]), pack_hi(lv[2],lv[3]),
                         pack_hi(lv[4],lv[5]), pack_hi(lv[6],lv[7]));
    }
    s16x8 WxH, WxL;
    {
        float wv[4], lv[4];
        #pragma unroll
        for (int e = 0; e < 4; ++e) {
            wv[e] = Wx[(4 * g + e) * DRNN + 16 * w + li];
            lv[e] = wv[e] - bf_trunc(wv[e]);
        }
        WxH = mk_frag(pack_hi(wv[0],wv[1]), pack_hi(wv[2],wv[3]), 0, 0);
        WxL = mk_frag(pack_hi(lv[0],lv[1]), pack_hi(lv[2],lv[3]), 0, 0);
    }
    // bias for D rows 16w + 4g + q
    const f32x4 bfr = *(const f32x4*)(bias + 16 * w + 4 * g);

    // x prefetch ring: lane (li,g) owns X[b0+li][t][4g..4g+3]
    const float* xrow = X + (size_t)(b0 + li) * TSEQ * DIN + 4 * g;
    f32x4 x0v = *(const f32x4*)(xrow);
    f32x4 xs1 = *(const f32x4*)(xrow + 1 * DIN);
    f32x4 xs2 = *(const f32x4*)(xrow + 2 * DIN);
    f32x4 xs3 = *(const f32x4*)(xrow + 3 * DIN);
    f32x4 xs4 = *(const f32x4*)(xrow + 4 * DIN);

    // zero exchange buffers (h_{-1} = 0)
    for (int idx = tid; idx < 2 * 32 * 17; idx += 256)
        (&hx[0][0][0])[idx] = 0u;

    // prologue: xacc = bias + x_0 @ Wx
    f32x4 xacc;
    {
        s16x8 BxH = mk_frag(pack_hi(x0v[0],x0v[1]), pack_hi(x0v[2],x0v[3]),0,0);
        s16x8 BxL = mk_frag(pack_hi(x0v[0]-bf_trunc(x0v[0]),
                                    x0v[1]-bf_trunc(x0v[1])),
                            pack_hi(x0v[2]-bf_trunc(x0v[2]),
                                    x0v[3]-bf_trunc(x0v[3])), 0, 0);
        f32x4 a = bfr;
        a = MFMA(WxH, BxH, a, 0,0,0);
        a = MFMA(WxL, BxH, a, 0,0,0);
        a = MFMA(WxH, BxL, a, 0,0,0);
        xacc = a;
    }
    __syncthreads();

    for (int tb = 0; tb < TSEQ; tb += 4) {
        STEP(hx[0], hx[1], xs1, tb);
        STEP(hx[1], hx[0], xs2, tb + 1);
        STEP(hx[0], hx[1], xs3, tb + 2);
        STEP(hx[1], hx[0], xs4, tb + 3);
    }

    // ---- MLP epilogue (fp32 scalar, feat already tanh'd in LDS) ----
    const int r  = tid & 15;   // batch row within block
    const int hc = tid >> 4;   // hidden-chunk 0..15 (8 hid units each)
    float acc8[8];
    #pragma unroll
    for (int u = 0; u < 8; ++u) acc8[u] = b1[hc * 8 + u];
    for (int s = 0; s < 3; ++s) {
        for (int kk = 0; kk < 64; ++kk) {
            float f = feat[(s * 16 + r) * FSTRIDE + kk];
            const float* wr = &W1[(s * 64 + kk) * 128 + hc * 8];
            f32x4 w0  = *(const f32x4*)wr;
            f32x4 w1v = *(const f32x4*)(wr + 4);
            acc8[0] += f * w0[0];  acc8[1] += f * w0[1];
            acc8[2] += f * w0[2];  acc8[3] += f * w0[3];
            acc8[4] += f * w1v[0]; acc8[5] += f * w1v[1];
            acc8[6] += f * w1v[2]; acc8[7] += f * w1v[3];
        }
    }
    float p = 0.f;
    #pragma unroll
    for (int u = 0; u < 8; ++u) p += tanh_fast(acc8[u]) * W2[hc * 8 + u];
    p += __shfl_xor(p, 16);
    p += __shfl_xor(p, 32);
    if (g == 0) wpart[w][li] = p;
    __syncthreads();
    if (tid < 16)
        out[b0 + tid] = wpart[0][tid] + wpart[1][tid] + wpart[2][tid]
                      + wpart[3][tid] + b2[0];
}

extern "C" void kernel_launch(void* const* d_in, const int* in_sizes, int n_in,
                              void* d_out, int out_size, void* d_ws, size_t ws_size,
                              hipStream_t stream) {
    const float* X    = (const float*)d_in[0];
    const float* Wx   = (const float*)d_in[1];
    const float* Wh   = (const float*)d_in[2];
    const float* bias = (const float*)d_in[3];
    const float* W1   = (const float*)d_in[4];
    const float* b1   = (const float*)d_in[5];
    const float* W2   = (const float*)d_in[6];
    const float* b2   = (const float*)d_in[7];
    rnn_w4<<<256, 256, 0, stream>>>(X, Wx, Wh, bias, W1, b1, W2, b2, (float*)d_out);
}

// Round 7
// 165.245 us; speedup vs baseline: 1.6540x; 1.0190x over previous
//
#include <hip/hip_runtime.h>
#include <cstdint>
#include <cstddef>

#define TSEQ 512
#define DRNN 64
#define DIN  16
#define FSTRIDE 66

typedef float  f32x4 __attribute__((ext_vector_type(4)));
typedef short  s16x8 __attribute__((ext_vector_type(8)));
typedef unsigned int u32x4 __attribute__((ext_vector_type(4)));

#define MFMA __builtin_amdgcn_mfma_f32_16x16x32_bf16

// word = (hi16(b) << 16) | hi16(a)   -- one v_perm_b32
__device__ __forceinline__ unsigned pack_hi(float a, float b) {
    return __builtin_amdgcn_perm(__builtin_bit_cast(unsigned, b),
                                 __builtin_bit_cast(unsigned, a), 0x07060302u);
}
__device__ __forceinline__ float bf_trunc(float v) {
    return __builtin_bit_cast(float, __builtin_bit_cast(unsigned, v) & 0xffff0000u);
}
__device__ __forceinline__ s16x8 mk_frag(unsigned w0, unsigned w1, unsigned w2, unsigned w3) {
    u32x4 u = {w0, w1, w2, w3};
    return __builtin_bit_cast(s16x8, u);
}
__device__ __forceinline__ float tanh_fast(float x) {
    float e = __builtin_amdgcn_exp2f(x * 2.885390082f);
    float r = __builtin_amdgcn_rcpf(1.0f + e);
    return __builtin_fmaf(-2.0f, r, 1.0f);
}

// Exchange buffer layout: dword index ((c*4+g)*16 + li)*4 + (s*2+r), where the
// pair-word (h[2p],h[2p+1]) with p = 16c + 8s + 2g + r lives at that slot.
// Consumer lane (g,li): c0 frag = b128 at (g*16+li)*4; c1 at ((4+g)*16+li)*4.
// Producer wave w, group g: writes r=0,1 at (((w>>1)*4+g)*16+li)*4 + (w&1)*2.
//
// One recurrence step. PR/PW: read/write halves (unsigned[512]).
// XS: register holding x_{TT+1} slice; refilled with x_{TT+5}.
// FS: compile-time feat-store slot (-1 = none, 0..2 = which of last 3 steps).
#define STEP(PR, PW, XS, TT, FS) do {                                         \
    /* B-fragments of h_{TT-1}: two contiguous 16B reads */                   \
    u32x4 r0_ = *(const u32x4*)&PR[(g * 16 + li) * 4];                        \
    u32x4 r1_ = *(const u32x4*)&PR[((4 + g) * 16 + li) * 4];                  \
    /* x-projection for NEXT step (independent -> hides LDS latency) */       \
    f32x4 xv_ = XS;                                                           \
    s16x8 BxH_ = mk_frag(pack_hi(xv_[0],xv_[1]), pack_hi(xv_[2],xv_[3]),0,0); \
    s16x8 BxL_ = mk_frag(pack_hi(xv_[0]-bf_trunc(xv_[0]),                     \
                                 xv_[1]-bf_trunc(xv_[1])),                    \
                         pack_hi(xv_[2]-bf_trunc(xv_[2]),                     \
                                 xv_[3]-bf_trunc(xv_[3])), 0, 0);             \
    f32x4 xn_ = bfr;                                                          \
    xn_ = MFMA(WxH, BxH_, xn_, 0,0,0);                                        \
    xn_ = MFMA(WxL, BxH_, xn_, 0,0,0);                                        \
    xn_ = MFMA(WxH, BxL_, xn_, 0,0,0);                                        \
    { int tl_ = (TT) + 5; if (tl_ > TSEQ - 1) tl_ = TSEQ - 1;                 \
      XS = *(const f32x4*)(xrow + (size_t)tl_ * DIN); }                       \
    /* 4 independent h-MFMAs, then a 2-level add tree */                      \
    s16x8 Bh0_ = __builtin_bit_cast(s16x8, r0_);                              \
    s16x8 Bh1_ = __builtin_bit_cast(s16x8, r1_);                              \
    f32x4 P_ = MFMA(WhH[0], Bh0_, xacc, 0,0,0);                               \
    f32x4 R_ = MFMA(WhL[0], Bh0_, zero4, 0,0,0);                              \
    f32x4 Q_ = MFMA(WhH[1], Bh1_, zero4, 0,0,0);                              \
    f32x4 S_ = MFMA(WhL[1], Bh1_, zero4, 0,0,0);                              \
    f32x4 d_ = (P_ + Q_) + (R_ + S_);                                         \
    float v0_ = tanh_fast(d_[0]), v1_ = tanh_fast(d_[1]);                     \
    float v2_ = tanh_fast(d_[2]), v3_ = tanh_fast(d_[3]);                     \
    { uint2 wv_; wv_.x = pack_hi(v0_, v1_); wv_.y = pack_hi(v2_, v3_);        \
      *(uint2*)&PW[((((w >> 1) * 4 + g) * 16 + li) * 4) + (w & 1) * 2] = wv_; }\
    if ((FS) >= 0) {                                                          \
        float* fp_ = &feat[((FS) * 16 + li) * FSTRIDE + 16 * w + 4 * g];      \
        fp_[0] = tanh_fast(v0_); fp_[1] = tanh_fast(v1_);                     \
        fp_[2] = tanh_fast(v2_); fp_[3] = tanh_fast(v3_);                     \
    }                                                                         \
    asm volatile("s_waitcnt lgkmcnt(0)" ::: "memory");                        \
    __builtin_amdgcn_sched_barrier(0);                                        \
    __builtin_amdgcn_s_barrier();                                             \
    __builtin_amdgcn_sched_barrier(0);                                        \
    xacc = xn_;                                                               \
} while (0)

__global__ __launch_bounds__(256, 1) void rnn_w4(
    const float* __restrict__ X,
    const float* __restrict__ Wx,
    const float* __restrict__ Wh,
    const float* __restrict__ bias,
    const float* __restrict__ W1,
    const float* __restrict__ b1,
    const float* __restrict__ W2,
    const float* __restrict__ b2,
    float* __restrict__ out)
{
    __shared__ unsigned hxn[2][512];          // pair-exchange, b128-friendly
    __shared__ float feat[3 * 16 * FSTRIDE];
    __shared__ float wpart[4][16];

    const int tid  = threadIdx.x;
    const int w    = tid >> 6;       // wave id = hidden tile mt
    const int lane = tid & 63;
    const int li   = lane & 15;      // batch row within tile
    const int g    = lane >> 4;      // k-slot group
    const int b0   = blockIdx.x * 16;
    const f32x4 zero4 = {0.f, 0.f, 0.f, 0.f};

    // ---- persistent A fragments for THIS wave's hidden tile (mt = w) ----
    // slot map: k(c,g,e) = c*32 + (e<4 ? 4g+e : 16+4g+(e-4)); value Wh[k][16w+li]
    s16x8 WhH[2], WhL[2];
    #pragma unroll
    for (int c = 0; c < 2; ++c) {
        float wv[8], lv[8];
        #pragma unroll
        for (int e = 0; e < 8; ++e) {
            int k = c * 32 + (e < 4 ? 4 * g + e : 16 + 4 * g + (e - 4));
            wv[e] = Wh[k * DRNN + 16 * w + li];
            lv[e] = wv[e] - bf_trunc(wv[e]);
        }
        WhH[c] = mk_frag(pack_hi(wv[0],wv[1]), pack_hi(wv[2],wv[3]),
                         pack_hi(wv[4],wv[5]), pack_hi(wv[6],wv[7]));
        WhL[c] = mk_frag(pack_hi(lv[0],lv[1]), pack_hi(lv[2],lv[3]),
                         pack_hi(lv[4],lv[5]), pack_hi(lv[6],lv[7]));
    }
    s16x8 WxH, WxL;
    {
        float wv[4], lv[4];
        #pragma unroll
        for (int e = 0; e < 4; ++e) {
            wv[e] = Wx[(4 * g + e) * DRNN + 16 * w + li];
            lv[e] = wv[e] - bf_trunc(wv[e]);
        }
        WxH = mk_frag(pack_hi(wv[0],wv[1]), pack_hi(wv[2],wv[3]), 0, 0);
        WxL = mk_frag(pack_hi(lv[0],lv[1]), pack_hi(lv[2],lv[3]), 0, 0);
    }
    // bias for D rows 16w + 4g + q
    const f32x4 bfr = *(const f32x4*)(bias + 16 * w + 4 * g);

    // x prefetch ring: lane (li,g) owns X[b0+li][t][4g..4g+3]
    const float* xrow = X + (size_t)(b0 + li) * TSEQ * DIN + 4 * g;
    f32x4 x0v = *(const f32x4*)(xrow);
    f32x4 xs1 = *(const f32x4*)(xrow + 1 * DIN);
    f32x4 xs2 = *(const f32x4*)(xrow + 2 * DIN);
    f32x4 xs3 = *(const f32x4*)(xrow + 3 * DIN);
    f32x4 xs4 = *(const f32x4*)(xrow + 4 * DIN);

    // zero exchange buffers (h_{-1} = 0)
    for (int idx = tid; idx < 2 * 512; idx += 256)
        (&hxn[0][0])[idx] = 0u;

    // prologue: xacc = bias + x_0 @ Wx
    f32x4 xacc;
    {
        s16x8 BxH = mk_frag(pack_hi(x0v[0],x0v[1]), pack_hi(x0v[2],x0v[3]),0,0);
        s16x8 BxL = mk_frag(pack_hi(x0v[0]-bf_trunc(x0v[0]),
                                    x0v[1]-bf_trunc(x0v[1])),
                            pack_hi(x0v[2]-bf_trunc(x0v[2]),
                                    x0v[3]-bf_trunc(x0v[3])), 0, 0);
        f32x4 a = bfr;
        a = MFMA(WxH, BxH, a, 0,0,0);
        a = MFMA(WxL, BxH, a, 0,0,0);
        a = MFMA(WxH, BxL, a, 0,0,0);
        xacc = a;
    }
    __syncthreads();

    unsigned* hx0 = &hxn[0][0];
    unsigned* hx1 = &hxn[1][0];

    // main loop: steps 0..507, no feat branch
    for (int tb = 0; tb < TSEQ - 4; tb += 4) {
        STEP(hx0, hx1, xs1, tb,     -1);
        STEP(hx1, hx0, xs2, tb + 1, -1);
        STEP(hx0, hx1, xs3, tb + 2, -1);
        STEP(hx1, hx0, xs4, tb + 3, -1);
    }
    // peeled tail: steps 508..511, feat capture at 509/510/511
    STEP(hx0, hx1, xs1, TSEQ - 4, -1);
    STEP(hx1, hx0, xs2, TSEQ - 3,  0);
    STEP(hx0, hx1, xs3, TSEQ - 2,  1);
    STEP(hx1, hx0, xs4, TSEQ - 1,  2);

    // ---- MLP epilogue (fp32 scalar, feat already tanh'd in LDS) ----
    __syncthreads();
    const int r  = tid & 15;   // batch row within block
    const int hc = tid >> 4;   // hidden-chunk 0..15 (8 hid units each)
    float acc8[8];
    #pragma unroll
    for (int u = 0; u < 8; ++u) acc8[u] = b1[hc * 8 + u];
    for (int s = 0; s < 3; ++s) {
        for (int kk = 0; kk < 64; ++kk) {
            float f = feat[(s * 16 + r) * FSTRIDE + kk];
            const float* wr = &W1[(s * 64 + kk) * 128 + hc * 8];
            f32x4 w0  = *(const f32x4*)wr;
            f32x4 w1v = *(const f32x4*)(wr + 4);
            acc8[0] += f * w0[0];  acc8[1] += f * w0[1];
            acc8[2] += f * w0[2];  acc8[3] += f * w0[3];
            acc8[4] += f * w1v[0]; acc8[5] += f * w1v[1];
            acc8[6] += f * w1v[2]; acc8[7] += f * w1v[3];
        }
    }
    float p = 0.f;
    #pragma unroll
    for (int u = 0; u < 8; ++u) p += tanh_fast(acc8[u]) * W2[hc * 8 + u];
    p += __shfl_xor(p, 16);
    p += __shfl_xor(p, 32);
    if (g == 0) wpart[w][li] = p;
    __syncthreads();
    if (tid < 16)
        out[b0 + tid] = wpart[0][tid] + wpart[1][tid] + wpart[2][tid]
                      + wpart[3][tid] + b2[0];
}

extern "C" void kernel_launch(void* const* d_in, const int* in_sizes, int n_in,
                              void* d_out, int out_size, void* d_ws, size_t ws_size,
                              hipStream_t stream) {
    const float* X    = (const float*)d_in[0];
    const float* Wx   = (const float*)d_in[1];
    const float* Wh   = (const float*)d_in[2];
    const float* bias = (const float*)d_in[3];
    const float* W1   = (const float*)d_in[4];
    const float* b1   = (const float*)d_in[5];
    const float* W2   = (const float*)d_in[6];
    const float* b2   = (const float*)d_in[7];
    rnn_w4<<<256, 256, 0, stream>>>(X, Wx, Wh, bias, W1, b1, W2, b2, (float*)d_out);
}

// Round 9
// 112.033 us; speedup vs baseline: 2.4397x; 1.4750x over previous
//
#include <hip/hip_runtime.h>
#include <cstdint>
#include <cstddef>

#define TSEQ 512
#define DRNN 64
#define DIN  16
#define FSTRIDE 66

typedef float    f32x4 __attribute__((ext_vector_type(4)));
typedef unsigned u32x4 __attribute__((ext_vector_type(4)));
typedef _Float16 f16x8 __attribute__((ext_vector_type(8)));

#define MFMA16(A, B, C) __builtin_amdgcn_mfma_f32_16x16x32_f16((A), (B), (C), 0, 0, 0)

// pack two f32 -> f16x2 dword (RTZ, single instr v_cvt_pkrtz_f16_f32)
__device__ __forceinline__ unsigned packh(float a, float b) {
    return __builtin_bit_cast(unsigned, __builtin_amdgcn_cvt_pkrtz(a, b));
}
__device__ __forceinline__ float tanh_fast(float x) {
    float e = __builtin_amdgcn_exp2f(x * 2.885390082f);
    float r = __builtin_amdgcn_rcpf(1.0f + e);
    return __builtin_fmaf(-2.0f, r, 1.0f);
}
// tanh of already-scaled argument d = 2*log2(e)*arg (scale folded into weights)
__device__ __forceinline__ float tanh_pre(float d) {
    float e = __builtin_amdgcn_exp2f(d);
    float r = __builtin_amdgcn_rcpf(1.0f + e);
    return __builtin_fmaf(-2.0f, r, 1.0f);
}

// Exchange layout (same as R7): pair-word of h pair p=16c+8s+2g+r at dword
// ((c*4+g)*16+li)*4 + s*2+r. Consumer (g,li): c0 = b128 @ (g*16+li)*4,
// c1 = b128 @ ((4+g)*16+li)*4. Producer wave w: r=0,1 at
// (((w>>1)*4+g)*16+li)*4 + (w&1)*2.
//
// One step, slot I (compile-time). PR/PW: read/write exchange halves.
// REFILL (compile-time): refill xacc[I] for t+16 and load x for t+32.
// FS (compile-time): feat slot or -1.
#define STEPF(I, PR, PW, FS, REFILL, TB) do {                                 \
    u32x4 r0_ = *(const u32x4*)&PR[(g * 16 + li) * 4];                        \
    u32x4 r1_ = *(const u32x4*)&PR[((4 + g) * 16 + li) * 4];                  \
    f32x4 xc_ = xacc[I];                                                      \
    if (REFILL) {                                                             \
        f32x4 xv_ = xreg[I];                                                  \
        u32x4 bx_ = { packh(xv_[0], xv_[1]), packh(xv_[2], xv_[3]), 0u, 0u }; \
        xacc[I] = MFMA16(WxF, __builtin_bit_cast(f16x8, bx_), bfrS);          \
        int tl_ = (TB) + 32 + (I); if (tl_ > TSEQ - 1) tl_ = TSEQ - 1;        \
        xreg[I] = *(const f32x4*)(xrow + (size_t)tl_ * DIN);                  \
    }                                                                         \
    f16x8 Bh0_ = __builtin_bit_cast(f16x8, r0_);                              \
    f16x8 Bh1_ = __builtin_bit_cast(f16x8, r1_);                              \
    f32x4 P_ = MFMA16(WhF0, Bh0_, xc_);                                       \
    f32x4 Q_ = MFMA16(WhF1, Bh1_, zero4);                                     \
    f32x4 d_ = P_ + Q_;                                                       \
    float v0_ = tanh_pre(d_[0]), v1_ = tanh_pre(d_[1]);                       \
    float v2_ = tanh_pre(d_[2]), v3_ = tanh_pre(d_[3]);                       \
    { uint2 wv_; wv_.x = packh(v0_, v1_); wv_.y = packh(v2_, v3_);            \
      *(uint2*)&PW[((((w >> 1) * 4 + g) * 16 + li) * 4) + (w & 1) * 2] = wv_; }\
    if ((FS) >= 0) {                                                          \
        float* fp_ = &feat[((FS) * 16 + li) * FSTRIDE + 16 * w + 4 * g];      \
        fp_[0] = tanh_fast(v0_); fp_[1] = tanh_fast(v1_);                     \
        fp_[2] = tanh_fast(v2_); fp_[3] = tanh_fast(v3_);                     \
    }                                                                         \
    asm volatile("s_waitcnt lgkmcnt(0)" ::: "memory");                        \
    __builtin_amdgcn_sched_barrier(0);                                        \
    __builtin_amdgcn_s_barrier();                                             \
    __builtin_amdgcn_sched_barrier(0);                                        \
} while (0)

__global__ __launch_bounds__(256, 1) void rnn_w4(
    const float* __restrict__ X,
    const float* __restrict__ Wx,
    const float* __restrict__ Wh,
    const float* __restrict__ bias,
    const float* __restrict__ W1,
    const float* __restrict__ b1,
    const float* __restrict__ W2,
    const float* __restrict__ b2,
    float* __restrict__ out)
{
    __shared__ unsigned hxn[2][512];          // pair-exchange, b128-friendly
    __shared__ float feat[3 * 16 * FSTRIDE];
    __shared__ float wpart[4][16];

    const int tid  = threadIdx.x;
    const int w    = tid >> 6;       // wave id = hidden tile mt
    const int lane = tid & 63;
    const int li   = lane & 15;      // batch row within tile
    const int g    = lane >> 4;      // k-slot group
    const int b0   = blockIdx.x * 16;
    const f32x4 zero4 = {0.f, 0.f, 0.f, 0.f};
    const float S = 2.885390082f;    // 2*log2(e), folded into Wh/Wx/bias

    // ---- persistent f16 A fragments for THIS wave's tile (mt = w) ----
    // slot map: k(c,g,e) = c*32 + (e<4 ? 4g+e : 16+4g+(e-4)); value S*Wh[k][16w+li]
    f16x8 WhF0, WhF1;
    {
        float wv[8];
        #pragma unroll
        for (int e = 0; e < 8; ++e) {
            int k = (e < 4 ? 4 * g + e : 16 + 4 * g + (e - 4));
            wv[e] = S * Wh[k * DRNN + 16 * w + li];
        }
        u32x4 u = { packh(wv[0],wv[1]), packh(wv[2],wv[3]),
                    packh(wv[4],wv[5]), packh(wv[6],wv[7]) };
        WhF0 = __builtin_bit_cast(f16x8, u);
        #pragma unroll
        for (int e = 0; e < 8; ++e) {
            int k = 32 + (e < 4 ? 4 * g + e : 16 + 4 * g + (e - 4));
            wv[e] = S * Wh[k * DRNN + 16 * w + li];
        }
        u32x4 v = { packh(wv[0],wv[1]), packh(wv[2],wv[3]),
                    packh(wv[4],wv[5]), packh(wv[6],wv[7]) };
        WhF1 = __builtin_bit_cast(f16x8, v);
    }
    f16x8 WxF;
    {
        float wv[4];
        #pragma unroll
        for (int e = 0; e < 4; ++e)
            wv[e] = S * Wx[(4 * g + e) * DRNN + 16 * w + li];
        u32x4 u = { packh(wv[0],wv[1]), packh(wv[2],wv[3]), 0u, 0u };
        WxF = __builtin_bit_cast(f16x8, u);
    }
    // scaled bias for D rows 16w + 4g + q
    f32x4 bfrS;
    {
        f32x4 b = *(const f32x4*)(bias + 16 * w + 4 * g);
        bfrS = b * S;
    }

    // x ring: lane (li,g) owns X[b0+li][t][4g..4g+3]
    const float* xrow = X + (size_t)(b0 + li) * TSEQ * DIN + 4 * g;
    f32x4 xreg[16], xacc[16];

    // zero exchange buffers (h_{-1} = 0)
    for (int idx = tid; idx < 2 * 512; idx += 256)
        (&hxn[0][0])[idx] = 0u;

    // prologue: xacc[i] = S*(bias + x_i @ Wx), i = 0..15; xreg[i] = x_{16+i}
    #pragma unroll
    for (int i = 0; i < 16; ++i)
        xreg[i] = *(const f32x4*)(xrow + (size_t)i * DIN);
    #pragma unroll
    for (int i = 0; i < 16; ++i) {
        f32x4 xv = xreg[i];
        u32x4 bx = { packh(xv[0], xv[1]), packh(xv[2], xv[3]), 0u, 0u };
        xacc[i] = MFMA16(WxF, __builtin_bit_cast(f16x8, bx), bfrS);
    }
    #pragma unroll
    for (int i = 0; i < 16; ++i)
        xreg[i] = *(const f32x4*)(xrow + (size_t)(16 + i) * DIN);
    __syncthreads();

    unsigned* hx0 = &hxn[0][0];
    unsigned* hx1 = &hxn[1][0];

    // main loop: steps 0..495 (31 blocks of 16); refill ring each step
    for (int tb = 0; tb < TSEQ - 16; tb += 16) {
        STEPF( 0, hx0, hx1, -1, 1, tb);
        STEPF( 1, hx1, hx0, -1, 1, tb);
        STEPF( 2, hx0, hx1, -1, 1, tb);
        STEPF( 3, hx1, hx0, -1, 1, tb);
        STEPF( 4, hx0, hx1, -1, 1, tb);
        STEPF( 5, hx1, hx0, -1, 1, tb);
        STEPF( 6, hx0, hx1, -1, 1, tb);
        STEPF( 7, hx1, hx0, -1, 1, tb);
        STEPF( 8, hx0, hx1, -1, 1, tb);
        STEPF( 9, hx1, hx0, -1, 1, tb);
        STEPF(10, hx0, hx1, -1, 1, tb);
        STEPF(11, hx1, hx0, -1, 1, tb);
        STEPF(12, hx0, hx1, -1, 1, tb);
        STEPF(13, hx1, hx0, -1, 1, tb);
        STEPF(14, hx0, hx1, -1, 1, tb);
        STEPF(15, hx1, hx0, -1, 1, tb);
    }
    // peeled final block: steps 496..511, no refill, feat at 509/510/511
    STEPF( 0, hx0, hx1, -1, 0, 0);
    STEPF( 1, hx1, hx0, -1, 0, 0);
    STEPF( 2, hx0, hx1, -1, 0, 0);
    STEPF( 3, hx1, hx0, -1, 0, 0);
    STEPF( 4, hx0, hx1, -1, 0, 0);
    STEPF( 5, hx1, hx0, -1, 0, 0);
    STEPF( 6, hx0, hx1, -1, 0, 0);
    STEPF( 7, hx1, hx0, -1, 0, 0);
    STEPF( 8, hx0, hx1, -1, 0, 0);
    STEPF( 9, hx1, hx0, -1, 0, 0);
    STEPF(10, hx0, hx1, -1, 0, 0);
    STEPF(11, hx1, hx0, -1, 0, 0);
    STEPF(12, hx0, hx1, -1, 0, 0);
    STEPF(13, hx1, hx0,  0, 0, 0);
    STEPF(14, hx0, hx1,  1, 0, 0);
    STEPF(15, hx1, hx0,  2, 0, 0);

    // ---- MLP epilogue (fp32 scalar, feat already tanh'd in LDS) ----
    __syncthreads();
    const int r  = tid & 15;   // batch row within block
    const int hc = tid >> 4;   // hidden-chunk 0..15 (8 hid units each)
    float acc8[8];
    #pragma unroll
    for (int u = 0; u < 8; ++u) acc8[u] = b1[hc * 8 + u];
    for (int s = 0; s < 3; ++s) {
        for (int kk = 0; kk < 64; ++kk) {
            float f = feat[(s * 16 + r) * FSTRIDE + kk];
            const float* wr = &W1[(s * 64 + kk) * 128 + hc * 8];
            f32x4 w0  = *(const f32x4*)wr;
            f32x4 w1v = *(const f32x4*)(wr + 4);
            acc8[0] += f * w0[0];  acc8[1] += f * w0[1];
            acc8[2] += f * w0[2];  acc8[3] += f * w0[3];
            acc8[4] += f * w1v[0]; acc8[5] += f * w1v[1];
            acc8[6] += f * w1v[2]; acc8[7] += f * w1v[3];
        }
    }
    float p = 0.f;
    #pragma unroll
    for (int u = 0; u < 8; ++u) p += tanh_fast(acc8[u]) * W2[hc * 8 + u];
    p += __shfl_xor(p, 16);
    p += __shfl_xor(p, 32);
    if (g == 0) wpart[w][li] = p;
    __syncthreads();
    if (tid < 16)
        out[b0 + tid] = wpart[0][tid] + wpart[1][tid] + wpart[2][tid]
                      + wpart[3][tid] + b2[0];
}

extern "C" void kernel_launch(void* const* d_in, const int* in_sizes, int n_in,
                              void* d_out, int out_size, void* d_ws, size_t ws_size,
                              hipStream_t stream) {
    const float* X    = (const float*)d_in[0];
    const float* Wx   = (const float*)d_in[1];
    const float* Wh   = (const float*)d_in[2];
    const float* bias = (const float*)d_in[3];
    const float* W1   = (const float*)d_in[4];
    const float* b1   = (const float*)d_in[5];
    const float* W2   = (const float*)d_in[6];
    const float* b2   = (const float*)d_in[7];
    rnn_w4<<<256, 256, 0, stream>>>(X, Wx, Wh, bias, W1, b1, W2, b2, (float*)d_out);
}